// Round 3
// baseline (15553.067 us; speedup 1.0000x reference)
//
#include <hip/hip_runtime.h>

#define NB 64      // batch
#define NL 512     // seq len
#define NT 64      // answer len
#define NH 512     // hidden
#define NE 256     // emb dim
#define NW 256     // attention weight dim

typedef __attribute__((ext_vector_type(8))) short bf16x8;
typedef __attribute__((ext_vector_type(4))) float f32x4;
typedef unsigned short u16;

__device__ __forceinline__ float bf2f(u16 v){
  union { unsigned u; float f; } x; x.u = ((unsigned)v) << 16; return x.f;
}
__device__ __forceinline__ u16 f2bf(float f){
  union { float f; unsigned u; } x; x.f = f;
  return (u16)((x.u + 0x7FFFu + ((x.u >> 16) & 1u)) >> 16);
}
__device__ __forceinline__ float sigm(float x){ return 1.f / (1.f + __expf(-x)); }
__device__ __forceinline__ float tanh_(float x){ float e = __expf(2.f * x); return 1.f - 2.f / (e + 1.f); }

// Grid barrier on a monotonic counter, agent-scope fences around relaxed atomics.
__device__ __forceinline__ void grid_barrier(int* cnt, int target){
  __syncthreads();
  __threadfence();   // release
  if(threadIdx.x == 0)
    __hip_atomic_fetch_add(cnt, 1, __ATOMIC_RELAXED, __HIP_MEMORY_SCOPE_AGENT);
  while(__hip_atomic_load(cnt, __ATOMIC_RELAXED, __HIP_MEMORY_SCOPE_AGENT) < target)
    __builtin_amdgcn_s_sleep(2);
  __threadfence();   // acquire
  __syncthreads();
}

__global__ void init_kernel(int* cnt){
  cnt[blockIdx.x * 256 + threadIdx.x] = 0;
}

// fp32 -> bf16 (round-to-nearest-even)
__global__ void cvt_kernel(const float* __restrict__ src, u16* __restrict__ dst, int n){
  const int i = blockIdx.x * 256 + threadIdx.x;
  if(i < n) dst[i] = f2bf(src[i]);
}

// ---------------------------------------------------------------------------
// Encoder: persistent, 32 blocks x 256 threads = 128 waves.
// btile = blockIdx&3 (XCD-friendly group swizzle), mtile = (blockIdx>>2)*4+wvl.
// Wave computes a 16(batch) x 16(hidden) tile of all 4 gates; c in registers.
// h in 2-slot rolling buffer. After the group barrier, waves with mtile<16
// fold blend1[t] = h_t @ W1^T + b1 into bl (bf16).
// ---------------------------------------------------------------------------
__global__ void __launch_bounds__(256, 1) enc_kernel(
    const int* __restrict__ ids, const u16* __restrict__ emb,
    const u16* __restrict__ Wih, const u16* __restrict__ Whh,
    const float* __restrict__ bih, const float* __restrict__ bhh,
    const u16* __restrict__ W1,  const float* __restrict__ b1,
    u16* hroll, u16* bl, int* cnt)
{
  const int lane = threadIdx.x & 63;
  const int col  = lane & 15;
  const int quad = lane >> 4;
  const int btile = blockIdx.x & 3;
  const int mtile = (blockIdx.x >> 2) * 4 + (threadIdx.x >> 6);
  const int j  = mtile * 16 + col;        // hidden index within a gate [0,512)
  const int ab = btile * 16 + col;        // A-row (batch) this lane loads
  int* bar = cnt + btile * 64;

  float bias[4];
  const u16* wh[4];
  const u16* wx[4];
#pragma unroll
  for(int g = 0; g < 4; ++g){
    const int row = g * NH + j;           // PyTorch gate order i,f,g,o
    bias[g] = bih[row] + bhh[row];
    wh[g] = Whh + (size_t)row * NH + quad * 8;
    wx[g] = Wih + (size_t)row * NE + quad * 8;
  }
  const int* idp = ids + ab * NL;         // ids is [B, L]
  const int n1 = mtile * 16 + col;        // blend1 column (mtile<16 only)
  const u16* w1r = W1 + (size_t)(mtile < 16 ? n1 : 0) * NH + quad * 8;
  const float b1f = (mtile < 16) ? b1[n1] : 0.f;
  float creg[4] = {0.f, 0.f, 0.f, 0.f};   // cell state, lane-owned

  for(int t = 0; t < NL; ++t){
    f32x4 z = {0.f, 0.f, 0.f, 0.f};
    f32x4 acc[4] = {z, z, z, z};

    // x part: A row = emb[ids[ab, t]]
    const int id = idp[t];
    const u16* xr = emb + (size_t)id * NE + quad * 8;
#pragma unroll
    for(int k0 = 0; k0 < NE; k0 += 32){
      const bf16x8 af = *(const bf16x8*)(xr + k0);
#pragma unroll
      for(int g = 0; g < 4; ++g)
        acc[g] = __builtin_amdgcn_mfma_f32_16x16x32_bf16(af, *(const bf16x8*)(wx[g] + k0), acc[g], 0, 0, 0);
    }
    // h part (h_{-1} = 0, skip at t==0); (t-1)&1 == (t+1)&1
    if(t > 0){
      const u16* ar = hroll + ((t + 1) & 1) * (NB * NH) + (size_t)ab * NH + quad * 8;
#pragma unroll
      for(int k0 = 0; k0 < NH; k0 += 32){
        const bf16x8 af = *(const bf16x8*)(ar + k0);
#pragma unroll
        for(int g = 0; g < 4; ++g)
          acc[g] = __builtin_amdgcn_mfma_f32_16x16x32_bf16(af, *(const bf16x8*)(wh[g] + k0), acc[g], 0, 0, 0);
      }
    }
    // epilogue: gates -> c (registers), h -> hroll[t&1]
    u16* ho = hroll + (t & 1) * (NB * NH);
#pragma unroll
    for(int r = 0; r < 4; ++r){
      const int ci = (btile * 16 + quad * 4 + r) * NH + j;
      const float gi = acc[0][r] + bias[0];
      const float gf = acc[1][r] + bias[1];
      const float gg = acc[2][r] + bias[2];
      const float go = acc[3][r] + bias[3];
      creg[r] = sigm(gf) * creg[r] + sigm(gi) * tanh_(gg);
      ho[ci] = f2bf(sigm(go) * tanh_(creg[r]));
    }
    grid_barrier(bar, 8 * (t + 1));

    // blend1[t] fold: rows = own btile, col n1; reads group-complete h_t
    if(mtile < 16){
      f32x4 a2 = {0.f, 0.f, 0.f, 0.f};
      const u16* ha = hroll + (t & 1) * (NB * NH) + (size_t)ab * NH + quad * 8;
#pragma unroll
      for(int k0 = 0; k0 < NH; k0 += 32)
        a2 = __builtin_amdgcn_mfma_f32_16x16x32_bf16(*(const bf16x8*)(ha + k0), *(const bf16x8*)(w1r + k0), a2, 0, 0, 0);
#pragma unroll
      for(int r = 0; r < 4; ++r){
        const int b = btile * 16 + quad * 4 + r;
        bl[((size_t)t * NB + b) * NW + n1] = f2bf(a2[r] + b1f);
      }
    }
  }
}

// ---------------------------------------------------------------------------
// Decoder: persistent, 64 blocks x 256 threads.
// Phase 1 (blocks 0..31): LSTM h/c update (x_dec == 0); c in registers,
// c0 = enc h_511 (hroll slot 1); h_{-1} = h0 (pre-converted into hdec slot 1).
// Full-grid barrier. Phase 2 (all 64 blocks, block = batch b):
// u = h@W2^T + b2 (fp32 W2); scores over L; log-softmax; write fp32 out.
// ---------------------------------------------------------------------------
__global__ void __launch_bounds__(256, 1) dec_kernel(
    const u16* __restrict__ Whh, const float* __restrict__ bih, const float* __restrict__ bhh,
    const float* __restrict__ W2, const float* __restrict__ b2,
    const float* __restrict__ vt, const float* __restrict__ vtb,
    const u16* __restrict__ bl,  const u16* __restrict__ hroll,
    u16* hdec, float* out, int* cnt)
{
  const int tid  = threadIdx.x;
  const int lane = tid & 63;
  const int wvl  = tid >> 6;
  const int gw   = blockIdx.x * 4 + wvl;
  const int col  = lane & 15;
  const int quad = lane >> 4;
  const int myb  = blockIdx.x;

  __shared__ float u_lds[NW];
  __shared__ float vt_lds[NW];
  __shared__ float s_lds[NL];
  __shared__ float red[8];

  const int btile = gw >> 5;
  const int mtile = gw & 31;
  const int j  = mtile * 16 + col;
  const int ab = btile * 16 + col;
  float bias[4] = {0.f, 0.f, 0.f, 0.f};
  const u16* wh[4] = {Whh, Whh, Whh, Whh};
  float creg[4] = {0.f, 0.f, 0.f, 0.f};
  if(gw < 128){
#pragma unroll
    for(int g = 0; g < 4; ++g){
      const int row = g * NH + j;
      bias[g] = bih[row] + bhh[row];
      wh[g] = Whh + (size_t)row * NH + quad * 8;
    }
#pragma unroll
    for(int r = 0; r < 4; ++r){    // c0 = enc_states[-1] = hroll slot 1
      const int ci = (btile * 16 + quad * 4 + r) * NH + j;
      creg[r] = bf2f(hroll[NB * NH + ci]);
    }
  }
  vt_lds[tid] = vt[tid];
  const float vtbf = vtb[0];
  const float* w2r = W2 + (size_t)tid * NH;
  const float b2f = b2[tid];

  for(int t = 0; t < NT; ++t){
    if(gw < 128){
      // slot (t-1)&1 == (t+1)&1 ; at t=0, slot 1 holds bf16(h0)
      const u16* hp = hdec + ((t + 1) & 1) * (NB * NH) + (size_t)ab * NH + quad * 8;
      f32x4 z = {0.f, 0.f, 0.f, 0.f};
      f32x4 acc[4] = {z, z, z, z};
#pragma unroll
      for(int k0 = 0; k0 < NH; k0 += 32){
        const bf16x8 af = *(const bf16x8*)(hp + k0);
#pragma unroll
        for(int g = 0; g < 4; ++g)
          acc[g] = __builtin_amdgcn_mfma_f32_16x16x32_bf16(af, *(const bf16x8*)(wh[g] + k0), acc[g], 0, 0, 0);
      }
      u16* hn = hdec + (t & 1) * (NB * NH);
#pragma unroll
      for(int r = 0; r < 4; ++r){
        const int ci = (btile * 16 + quad * 4 + r) * NH + j;
        const float gi = acc[0][r] + bias[0];
        const float gf = acc[1][r] + bias[1];
        const float gg = acc[2][r] + bias[2];
        const float go = acc[3][r] + bias[3];
        creg[r] = sigm(gf) * creg[r] + sigm(gi) * tanh_(gg);
        hn[ci] = f2bf(sigm(go) * tanh_(creg[r]));
      }
    }
    grid_barrier(cnt, 64 * (t + 1));

    // ---- phase 2: attention + log-softmax for batch column myb ----
    {
      const u16* hr = hdec + (t & 1) * (NB * NH) + (size_t)myb * NH;
      float s = b2f;
      for(int k0 = 0; k0 < NH; k0 += 8){
        const bf16x8 hv = *(const bf16x8*)(hr + k0);
#pragma unroll
        for(int q = 0; q < 8; ++q)
          s += bf2f((u16)hv[q]) * w2r[k0 + q];
      }
      u_lds[tid] = s;
    }
    __syncthreads();

    for(int l = wvl; l < NL; l += 4){
      const u16* br = bl + (size_t)(l * NB + myb) * NW;
      float p = 0.f;
#pragma unroll
      for(int q = 0; q < 4; ++q){
        const int w = lane + 64 * q;
        p += vt_lds[w] * tanh_(bf2f(br[w]) + u_lds[w]);
      }
#pragma unroll
      for(int off = 32; off > 0; off >>= 1) p += __shfl_xor(p, off, 64);
      if(lane == 0) s_lds[l] = p + vtbf;
    }
    __syncthreads();

    // log-softmax over L = 512 (thread owns l = tid and tid+256)
    const float a0 = s_lds[tid];
    const float a1 = s_lds[tid + 256];
    float mx = fmaxf(a0, a1);
#pragma unroll
    for(int off = 32; off > 0; off >>= 1) mx = fmaxf(mx, __shfl_xor(mx, off, 64));
    if(lane == 0) red[wvl] = mx;
    __syncthreads();
    mx = fmaxf(fmaxf(red[0], red[1]), fmaxf(red[2], red[3]));
    float es = __expf(a0 - mx) + __expf(a1 - mx);
#pragma unroll
    for(int off = 32; off > 0; off >>= 1) es += __shfl_xor(es, off, 64);
    if(lane == 0) red[4 + wvl] = es;
    __syncthreads();
    const float lse = mx + logf(red[4] + red[5] + red[6] + red[7]);
    out[((size_t)tid * NB + myb) * NT + t]         = a0 - lse;
    out[((size_t)(tid + 256) * NB + myb) * NT + t] = a1 - lse;
    __syncthreads();
  }
}

// ---------------------------------------------------------------------------
extern "C" void kernel_launch(void* const* d_in, const int* in_sizes, int n_in,
                              void* d_out, int out_size, void* d_ws, size_t ws_size,
                              hipStream_t stream)
{
  (void)in_sizes; (void)n_in; (void)out_size; (void)ws_size;
  const int*   ids  = (const int*)d_in[0];
  const float* emb  = (const float*)d_in[1];
  const float* eWih = (const float*)d_in[2];
  const float* eWhh = (const float*)d_in[3];
  const float* ebih = (const float*)d_in[4];
  const float* ebhh = (const float*)d_in[5];
  /* d_in[6] = dec_Wih: unused (decoder input is identically zero) */
  const float* dWhh = (const float*)d_in[7];
  const float* dbih = (const float*)d_in[8];
  const float* dbhh = (const float*)d_in[9];
  const float* W1   = (const float*)d_in[10];
  const float* b1   = (const float*)d_in[11];
  const float* W2   = (const float*)d_in[12];
  const float* b2   = (const float*)d_in[13];
  const float* vt   = (const float*)d_in[14];
  const float* vtb  = (const float*)d_in[15];
  const float* h0   = (const float*)d_in[16];

  // workspace: ~27.6 MB
  char* ws = (char*)d_ws;
  u16* bl     = (u16*)ws; ws += (size_t)NL * NB * NW * 2;   // blend1 bf16  16.78 MB
  u16* hroll  = (u16*)ws; ws += (size_t)2 * NB * NH * 2;    // enc h double-buffer
  u16* hdec   = (u16*)ws; ws += (size_t)2 * NB * NH * 2;    // dec h double-buffer
  u16* emb_b  = (u16*)ws; ws += (size_t)10000 * NE * 2;     // bf16 emb     5.12 MB
  u16* eWih_b = (u16*)ws; ws += (size_t)4 * NH * NE * 2;    // 1.05 MB
  u16* eWhh_b = (u16*)ws; ws += (size_t)4 * NH * NH * 2;    // 2.10 MB
  u16* dWhh_b = (u16*)ws; ws += (size_t)4 * NH * NH * 2;    // 2.10 MB
  u16* W1_b   = (u16*)ws; ws += (size_t)NW * NH * 2;        // 0.26 MB
  int* cnt    = (int*)ws;                                   // 512 barrier counters

  hipLaunchKernelGGL(init_kernel, dim3(2), dim3(256), 0, stream, cnt);
  hipLaunchKernelGGL(cvt_kernel, dim3((10000 * NE + 255) / 256), dim3(256), 0, stream, emb,  emb_b,  10000 * NE);
  hipLaunchKernelGGL(cvt_kernel, dim3((4 * NH * NE + 255) / 256), dim3(256), 0, stream, eWih, eWih_b, 4 * NH * NE);
  hipLaunchKernelGGL(cvt_kernel, dim3((4 * NH * NH + 255) / 256), dim3(256), 0, stream, eWhh, eWhh_b, 4 * NH * NH);
  hipLaunchKernelGGL(cvt_kernel, dim3((4 * NH * NH + 255) / 256), dim3(256), 0, stream, dWhh, dWhh_b, 4 * NH * NH);
  hipLaunchKernelGGL(cvt_kernel, dim3((NW * NH + 255) / 256), dim3(256), 0, stream, W1,   W1_b,   NW * NH);
  hipLaunchKernelGGL(cvt_kernel, dim3((NB * NH + 255) / 256), dim3(256), 0, stream, h0, hdec + NB * NH, NB * NH);

  hipLaunchKernelGGL(enc_kernel, dim3(32), dim3(256), 0, stream,
                     ids, emb_b, eWih_b, eWhh_b, ebih, ebhh, W1_b, b1, hroll, bl, cnt);
  hipLaunchKernelGGL(dec_kernel, dim3(64), dim3(256), 0, stream,
                     dWhh_b, dbih, dbhh, W2, b2, vt, vtb, bl, hroll, hdec,
                     (float*)d_out, cnt + 256);
}

// Round 4
// 15390.160 us; speedup vs baseline: 1.0106x; 1.0106x over previous
//
#include <hip/hip_runtime.h>

#define NB 64      // batch
#define NL 512     // seq len
#define NT 64      // answer len
#define NH 512     // hidden
#define NE 256     // emb dim
#define NW 256     // attention weight dim

typedef __attribute__((ext_vector_type(8))) short bf16x8;
typedef __attribute__((ext_vector_type(4))) float f32x4;
typedef unsigned short u16;
typedef unsigned int u32;
typedef unsigned long long u64;

__device__ __forceinline__ float bf2f(u16 v){
  union { u32 u; float f; } x; x.u = ((u32)v) << 16; return x.f;
}
__device__ __forceinline__ u16 f2bf(float f){
  union { float f; u32 u; } x; x.f = f;
  return (u16)((x.u + 0x7FFFu + ((x.u >> 16) & 1u)) >> 16);
}
__device__ __forceinline__ float sigm(float x){ return 1.f / (1.f + __expf(-x)); }
__device__ __forceinline__ float tanh_(float x){ float e = __expf(2.f * x); return 1.f - 2.f / (e + 1.f); }

// device-scope (L3 coherence point) data movement — no fences anywhere
__device__ __forceinline__ u64 ald64(const u64* p){
  return __hip_atomic_load(p, __ATOMIC_RELAXED, __HIP_MEMORY_SCOPE_AGENT);
}
__device__ __forceinline__ void ast32(u32* p, u32 v){
  __hip_atomic_store(p, v, __ATOMIC_RELAXED, __HIP_MEMORY_SCOPE_AGENT);
}
__device__ __forceinline__ int aldc(const int* p){
  return __hip_atomic_load(p, __ATOMIC_RELAXED, __HIP_MEMORY_SCOPE_AGENT);
}
__device__ __forceinline__ bf16x8 mk8(u64 a, u64 b){
  union { u64 q[2]; bf16x8 v; } u; u.q[0] = a; u.q[1] = b; return u.v;
}
// all of this block's stores have reached the coherence point
__device__ __forceinline__ void drain_stores(){
  asm volatile("s_waitcnt vmcnt(0)" ::: "memory");
  __syncthreads();
}

__global__ void init_kernel(int* cnt){
  cnt[blockIdx.x * 256 + threadIdx.x] = 0;
}

// fp32 -> bf16 (round-to-nearest-even)
__global__ void cvt_kernel(const float* __restrict__ src, u16* __restrict__ dst, int n){
  const int i = blockIdx.x * 256 + threadIdx.x;
  if(i < n) dst[i] = f2bf(src[i]);
}

// ---------------------------------------------------------------------------
// Encoder: persistent, 32 blocks x 256 threads = 128 waves.
// btile = blockIdx&3, mtile = (blockIdx>>2)*4 + wave. Wave computes a
// 16(batch) x 16(hidden) tile of all 4 gates; cell state in registers.
// h ring: 3 slots, written with device-scope atomic u32 stores (bf16 pairs,
// even lanes after a shfl pack), read with device-scope atomic u64 loads.
// Barrier: per-btile-group counter; thread0 adds after drain, thread0 polls.
// x-part of step t+1 is computed between the add and the poll.
// ---------------------------------------------------------------------------
__global__ void __launch_bounds__(256, 1) enc_kernel(
    const int* __restrict__ ids, const u16* __restrict__ emb,
    const u16* __restrict__ Wih, const u16* __restrict__ Whh,
    const float* __restrict__ bih, const float* __restrict__ bhh,
    const u16* __restrict__ W1,  const float* __restrict__ b1,
    u16* hroll, u16* bl, int* cnt)
{
  const int lane = threadIdx.x & 63;
  const int col  = lane & 15;
  const int quad = lane >> 4;
  const int btile = blockIdx.x & 3;
  const int mtile = (blockIdx.x >> 2) * 4 + (threadIdx.x >> 6);
  const int j  = mtile * 16 + col;        // hidden index within a gate [0,512)
  const int ab = btile * 16 + col;        // A-row (batch) this lane loads
  int* bar = cnt + btile * 64;

  float bias[4];
  const u16* wh[4];
  const u16* wx[4];
#pragma unroll
  for(int g = 0; g < 4; ++g){
    const int row = g * NH + j;           // PyTorch gate order i,f,g,o
    bias[g] = bih[row] + bhh[row];
    wh[g] = Whh + (size_t)row * NH + quad * 8;
    wx[g] = Wih + (size_t)row * NE + quad * 8;
  }
  const int* idp = ids + ab * NL;         // ids is [B, L]
  const int n1 = mtile * 16 + col;        // blend1 column (mtile<16 only)
  const u16* w1r = W1 + (size_t)(mtile < 16 ? n1 : 0) * NH + quad * 8;
  const float b1f = (mtile < 16) ? b1[n1] : 0.f;
  float creg[4] = {0.f, 0.f, 0.f, 0.f};   // cell state, lane-owned

  u64 hb[32];                             // h_{t-1} fragment (16B x 16 chunks)
  f32x4 acc[4];

  // x-part of t=0
  {
    const u16* xr = emb + (size_t)idp[0] * NE + quad * 8;
#pragma unroll
    for(int g = 0; g < 4; ++g) acc[g] = (f32x4){0.f, 0.f, 0.f, 0.f};
#pragma unroll
    for(int k0 = 0; k0 < NE; k0 += 32){
      const bf16x8 af = *(const bf16x8*)(xr + k0);
#pragma unroll
      for(int g = 0; g < 4; ++g)
        acc[g] = __builtin_amdgcn_mfma_f32_16x16x32_bf16(af, *(const bf16x8*)(wx[g] + k0), acc[g], 0, 0, 0);
    }
  }

  for(int t = 0; t < NL; ++t){
    // h part (hb holds h_{t-1}, loaded at end of previous iteration)
    if(t > 0){
#pragma unroll
      for(int i = 0; i < 16; ++i){
        const bf16x8 af = mk8(hb[2 * i], hb[2 * i + 1]);
#pragma unroll
        for(int g = 0; g < 4; ++g)
          acc[g] = __builtin_amdgcn_mfma_f32_16x16x32_bf16(af, *(const bf16x8*)(wh[g] + 32 * i), acc[g], 0, 0, 0);
      }
    }
    // epilogue: gates -> c (registers), h -> hroll[t%3] via atomic u32 stores
    u16* ho = hroll + (t % 3) * (NB * NH);
#pragma unroll
    for(int r = 0; r < 4; ++r){
      const float gi = acc[0][r] + bias[0];
      const float gf = acc[1][r] + bias[1];
      const float gg = acc[2][r] + bias[2];
      const float go = acc[3][r] + bias[3];
      creg[r] = sigm(gf) * creg[r] + sigm(gi) * tanh_(gg);
      const u32 my = f2bf(sigm(go) * tanh_(creg[r]));
      const u32 ot = (u32)__shfl_xor((int)my, 1, 64);
      if((lane & 1) == 0){
        const int row = btile * 16 + quad * 4 + r;
        ast32((u32*)(ho + (size_t)row * NH + j), my | (ot << 16));
      }
    }
    drain_stores();
    if(threadIdx.x == 0)
      __hip_atomic_fetch_add(bar, 1, __ATOMIC_RELAXED, __HIP_MEMORY_SCOPE_AGENT);

    // overlap: x-part of t+1 while the group finishes
    if(t + 1 < NL){
      const u16* xr = emb + (size_t)idp[t + 1] * NE + quad * 8;
#pragma unroll
      for(int g = 0; g < 4; ++g) acc[g] = (f32x4){0.f, 0.f, 0.f, 0.f};
#pragma unroll
      for(int k0 = 0; k0 < NE; k0 += 32){
        const bf16x8 af = *(const bf16x8*)(xr + k0);
#pragma unroll
        for(int g = 0; g < 4; ++g)
          acc[g] = __builtin_amdgcn_mfma_f32_16x16x32_bf16(af, *(const bf16x8*)(wx[g] + k0), acc[g], 0, 0, 0);
      }
    }
    // wait for group: h_t complete device-visible
    if(threadIdx.x == 0){ while(aldc(bar) < 8 * (t + 1)) {} }
    __syncthreads();

    // load h_t fragment (used by blend(t) now and h-part(t+1) next iter)
    {
      const u16* ha = hroll + (t % 3) * (NB * NH) + (size_t)ab * NH + quad * 8;
#pragma unroll
      for(int i = 0; i < 16; ++i){
        const u64* p = (const u64*)(ha + 32 * i);
        hb[2 * i]     = ald64(p);
        hb[2 * i + 1] = ald64(p + 1);
      }
    }
    // blend1[t] fold (bf16, normal stores — consumed only after kernel end)
    if(mtile < 16){
      f32x4 a2 = {0.f, 0.f, 0.f, 0.f};
#pragma unroll
      for(int i = 0; i < 16; ++i)
        a2 = __builtin_amdgcn_mfma_f32_16x16x32_bf16(mk8(hb[2 * i], hb[2 * i + 1]), *(const bf16x8*)(w1r + 32 * i), a2, 0, 0, 0);
#pragma unroll
      for(int r = 0; r < 4; ++r){
        const int b = btile * 16 + quad * 4 + r;
        bl[((size_t)t * NB + b) * NW + n1] = f2bf(a2[r] + b1f);
      }
    }
  }
}

// ---------------------------------------------------------------------------
// Decoder: persistent, 64 blocks x 256 threads.
// Producers (blocks 0..31): LSTM update (x_dec == 0), h via atomic stores into
// a 2-slot ring, cntA += 1 per step. All blocks: poll cntA, stage h row myb
// through LDS (atomic u64 loads), attention + log-softmax, cntB += 1
// (phase-2 completion — licenses slot overwrite two steps later).
// ---------------------------------------------------------------------------
__global__ void __launch_bounds__(256, 1) dec_kernel(
    const u16* __restrict__ Whh, const float* __restrict__ bih, const float* __restrict__ bhh,
    const float* __restrict__ W2, const float* __restrict__ b2,
    const float* __restrict__ vt, const float* __restrict__ vtb,
    const u16* __restrict__ bl,  const u16* __restrict__ hroll,
    u16* hdec, float* out, int* cntA)
{
  int* cntB = cntA + 64;
  const int tid  = threadIdx.x;
  const int lane = tid & 63;
  const int wvl  = tid >> 6;
  const int col  = lane & 15;
  const int quad = lane >> 4;
  const int myb  = blockIdx.x;
  const bool producer = (blockIdx.x < 32);

  __shared__ u64  hld[NH / 4];   // this block's h row (1 KB)
  __shared__ float u_lds[NW];
  __shared__ float vt_lds[NW];
  __shared__ float s_lds[NL];
  __shared__ float red[8];

  const int gw   = blockIdx.x * 4 + wvl;
  const int btile = gw >> 5;
  const int mtile = gw & 31;
  const int j  = mtile * 16 + col;
  const int ab = btile * 16 + col;
  float bias[4] = {0.f, 0.f, 0.f, 0.f};
  const u16* wh[4] = {Whh, Whh, Whh, Whh};
  float creg[4] = {0.f, 0.f, 0.f, 0.f};
  if(producer){
#pragma unroll
    for(int g = 0; g < 4; ++g){
      const int row = g * NH + j;
      bias[g] = bih[row] + bhh[row];
      wh[g] = Whh + (size_t)row * NH + quad * 8;
    }
    // c0 = enc h_511, stored in hroll slot 511%3 == 1 (normal loads: kernel boundary)
#pragma unroll
    for(int r = 0; r < 4; ++r){
      const int ci = (btile * 16 + quad * 4 + r) * NH + j;
      creg[r] = bf2f(hroll[(NB * NH) + ci]);
    }
  }
  vt_lds[tid] = vt[tid];
  const float vtbf = vtb[0];
  const float* w2r = W2 + (size_t)tid * NH;
  const float b2f = b2[tid];

  for(int t = 0; t < NT; ++t){
    if(producer){
      if(tid == 0){
        while(aldc(cntA) < 32 * t) {}                       // h_{t-1} ready
        if(t >= 2){ while(aldc(cntB) < 64 * (t - 1)) {} }   // phase2(t-2) done
      }
      __syncthreads();
      // h_{t-1} from slot (t+1)&1 (t=0: bf16(h0) pre-staged there)
      u64 hb[32];
      {
        const u16* hp = hdec + ((t + 1) & 1) * (NB * NH) + (size_t)ab * NH + quad * 8;
#pragma unroll
        for(int i = 0; i < 16; ++i){
          const u64* p = (const u64*)(hp + 32 * i);
          hb[2 * i]     = ald64(p);
          hb[2 * i + 1] = ald64(p + 1);
        }
      }
      f32x4 z = {0.f, 0.f, 0.f, 0.f};
      f32x4 acc[4] = {z, z, z, z};
#pragma unroll
      for(int i = 0; i < 16; ++i){
        const bf16x8 af = mk8(hb[2 * i], hb[2 * i + 1]);
#pragma unroll
        for(int g = 0; g < 4; ++g)
          acc[g] = __builtin_amdgcn_mfma_f32_16x16x32_bf16(af, *(const bf16x8*)(wh[g] + 32 * i), acc[g], 0, 0, 0);
      }
      u16* hn = hdec + (t & 1) * (NB * NH);
#pragma unroll
      for(int r = 0; r < 4; ++r){
        const float gi = acc[0][r] + bias[0];
        const float gf = acc[1][r] + bias[1];
        const float gg = acc[2][r] + bias[2];
        const float go = acc[3][r] + bias[3];
        creg[r] = sigm(gf) * creg[r] + sigm(gi) * tanh_(gg);
        const u32 my = f2bf(sigm(go) * tanh_(creg[r]));
        const u32 ot = (u32)__shfl_xor((int)my, 1, 64);
        if((lane & 1) == 0){
          const int row = btile * 16 + quad * 4 + r;
          ast32((u32*)(hn + (size_t)row * NH + j), my | (ot << 16));
        }
      }
      drain_stores();
      if(tid == 0)
        __hip_atomic_fetch_add(cntA, 1, __ATOMIC_RELAXED, __HIP_MEMORY_SCOPE_AGENT);
    }

    // ---- all blocks: wait for h_t, then attention for batch column myb ----
    if(tid == 0){ while(aldc(cntA) < 32 * (t + 1)) {} }
    __syncthreads();
    if(tid < NH / 4)
      hld[tid] = ald64((const u64*)(hdec + (t & 1) * (NB * NH) + (size_t)myb * NH) + tid);
    __syncthreads();

    // u[tid] = b2[tid] + h . W2[tid,:]
    {
      float s = b2f;
#pragma unroll 8
      for(int kk = 0; kk < NH / 4; ++kk){
        const u64 v = hld[kk];
        s += bf2f((u16)(v      )) * w2r[kk * 4    ];
        s += bf2f((u16)(v >> 16)) * w2r[kk * 4 + 1];
        s += bf2f((u16)(v >> 32)) * w2r[kk * 4 + 2];
        s += bf2f((u16)(v >> 48)) * w2r[kk * 4 + 3];
      }
      u_lds[tid] = s;
    }
    __syncthreads();

    for(int l = wvl; l < NL; l += 4){
      const u16* br = bl + (size_t)(l * NB + myb) * NW;
      float p = 0.f;
#pragma unroll
      for(int q = 0; q < 4; ++q){
        const int w = lane + 64 * q;
        p += vt_lds[w] * tanh_(bf2f(br[w]) + u_lds[w]);
      }
#pragma unroll
      for(int off = 32; off > 0; off >>= 1) p += __shfl_xor(p, off, 64);
      if(lane == 0) s_lds[l] = p + vtbf;
    }
    __syncthreads();

    // log-softmax over L = 512 (thread owns l = tid and tid+256)
    const float a0 = s_lds[tid];
    const float a1 = s_lds[tid + 256];
    float mx = fmaxf(a0, a1);
#pragma unroll
    for(int off = 32; off > 0; off >>= 1) mx = fmaxf(mx, __shfl_xor(mx, off, 64));
    if(lane == 0) red[wvl] = mx;
    __syncthreads();
    mx = fmaxf(fmaxf(red[0], red[1]), fmaxf(red[2], red[3]));
    float es = __expf(a0 - mx) + __expf(a1 - mx);
#pragma unroll
    for(int off = 32; off > 0; off >>= 1) es += __shfl_xor(es, off, 64);
    if(lane == 0) red[4 + wvl] = es;
    __syncthreads();
    const float lse = mx + logf(red[4] + red[5] + red[6] + red[7]);
    out[((size_t)tid * NB + myb) * NT + t]         = a0 - lse;
    out[((size_t)(tid + 256) * NB + myb) * NT + t] = a1 - lse;
    __syncthreads();
    if(tid == 0)
      __hip_atomic_fetch_add(cntB, 1, __ATOMIC_RELAXED, __HIP_MEMORY_SCOPE_AGENT);
  }
}

// ---------------------------------------------------------------------------
extern "C" void kernel_launch(void* const* d_in, const int* in_sizes, int n_in,
                              void* d_out, int out_size, void* d_ws, size_t ws_size,
                              hipStream_t stream)
{
  (void)in_sizes; (void)n_in; (void)out_size; (void)ws_size;
  const int*   ids  = (const int*)d_in[0];
  const float* emb  = (const float*)d_in[1];
  const float* eWih = (const float*)d_in[2];
  const float* eWhh = (const float*)d_in[3];
  const float* ebih = (const float*)d_in[4];
  const float* ebhh = (const float*)d_in[5];
  /* d_in[6] = dec_Wih: unused (decoder input is identically zero) */
  const float* dWhh = (const float*)d_in[7];
  const float* dbih = (const float*)d_in[8];
  const float* dbhh = (const float*)d_in[9];
  const float* W1   = (const float*)d_in[10];
  const float* b1   = (const float*)d_in[11];
  const float* W2   = (const float*)d_in[12];
  const float* b2   = (const float*)d_in[13];
  const float* vt   = (const float*)d_in[14];
  const float* vtb  = (const float*)d_in[15];
  const float* h0   = (const float*)d_in[16];

  // workspace: ~27.8 MB
  char* ws = (char*)d_ws;
  u16* bl     = (u16*)ws; ws += (size_t)NL * NB * NW * 2;   // blend1 bf16  16.78 MB
  u16* hroll  = (u16*)ws; ws += (size_t)3 * NB * NH * 2;    // enc h ring (3 slots)
  u16* hdec   = (u16*)ws; ws += (size_t)2 * NB * NH * 2;    // dec h ring (2 slots)
  u16* emb_b  = (u16*)ws; ws += (size_t)10000 * NE * 2;     // bf16 emb     5.12 MB
  u16* eWih_b = (u16*)ws; ws += (size_t)4 * NH * NE * 2;    // 1.05 MB
  u16* eWhh_b = (u16*)ws; ws += (size_t)4 * NH * NH * 2;    // 2.10 MB
  u16* dWhh_b = (u16*)ws; ws += (size_t)4 * NH * NH * 2;    // 2.10 MB
  u16* W1_b   = (u16*)ws; ws += (size_t)NW * NH * 2;        // 0.26 MB
  int* cnt    = (int*)ws;                                   // 512 barrier counters

  hipLaunchKernelGGL(init_kernel, dim3(2), dim3(256), 0, stream, cnt);
  hipLaunchKernelGGL(cvt_kernel, dim3((10000 * NE + 255) / 256), dim3(256), 0, stream, emb,  emb_b,  10000 * NE);
  hipLaunchKernelGGL(cvt_kernel, dim3((4 * NH * NE + 255) / 256), dim3(256), 0, stream, eWih, eWih_b, 4 * NH * NE);
  hipLaunchKernelGGL(cvt_kernel, dim3((4 * NH * NH + 255) / 256), dim3(256), 0, stream, eWhh, eWhh_b, 4 * NH * NH);
  hipLaunchKernelGGL(cvt_kernel, dim3((4 * NH * NH + 255) / 256), dim3(256), 0, stream, dWhh, dWhh_b, 4 * NH * NH);
  hipLaunchKernelGGL(cvt_kernel, dim3((NW * NH + 255) / 256), dim3(256), 0, stream, W1,   W1_b,   NW * NH);
  hipLaunchKernelGGL(cvt_kernel, dim3((NB * NH + 255) / 256), dim3(256), 0, stream, h0, hdec + NB * NH, NB * NH);

  hipLaunchKernelGGL(enc_kernel, dim3(32), dim3(256), 0, stream,
                     ids, emb_b, eWih_b, eWhh_b, ebih, ebhh, W1_b, b1, hroll, bl, cnt);
  hipLaunchKernelGGL(dec_kernel, dim3(64), dim3(256), 0, stream,
                     dWhh_b, dbih, dbhh, W2, b2, vt, vtb, bl, hroll, hdec,
                     (float*)d_out, cnt + 256);
}